// Round 1
// baseline (1258.854 us; speedup 1.0000x reference)
//
#include <hip/hip_runtime.h>

#define NN   4096
#define EMB  16
#define CIN  64
#define COUT 64
#define BB   16

// ---------------------------------------------------------------------------
// Kernel 1: A = softmax(relu(E @ E^T), axis=1).  One block per row.
// ---------------------------------------------------------------------------
__global__ __launch_bounds__(256) void adj_softmax_kernel(
    const float* __restrict__ E, float* __restrict__ A)
{
    const int n = blockIdx.x;
    const int t = threadIdx.x;
    __shared__ float en[EMB];
    __shared__ float red[4];

    if (t < EMB) en[t] = E[(size_t)n * EMB + t];
    __syncthreads();

    float v[16];
    float mx = 0.0f;  // relu >= 0, so row max >= 0
    #pragma unroll
    for (int r = 0; r < 16; ++r) {
        int m = t + r * 256;
        const float4* ep = reinterpret_cast<const float4*>(E + (size_t)m * EMB);
        float4 e0 = ep[0], e1 = ep[1], e2 = ep[2], e3 = ep[3];
        float d = e0.x*en[0] + e0.y*en[1] + e0.z*en[2]  + e0.w*en[3]
                + e1.x*en[4] + e1.y*en[5] + e1.z*en[6]  + e1.w*en[7]
                + e2.x*en[8] + e2.y*en[9] + e2.z*en[10] + e2.w*en[11]
                + e3.x*en[12]+ e3.y*en[13]+ e3.z*en[14] + e3.w*en[15];
        d = fmaxf(d, 0.0f);
        v[r] = d;
        mx = fmaxf(mx, d);
    }
    // wave reduce max, then across 4 waves
    #pragma unroll
    for (int off = 32; off > 0; off >>= 1) mx = fmaxf(mx, __shfl_xor(mx, off, 64));
    if ((t & 63) == 0) red[t >> 6] = mx;
    __syncthreads();
    mx = fmaxf(fmaxf(red[0], red[1]), fmaxf(red[2], red[3]));
    __syncthreads();  // everyone done reading red before reuse

    float s = 0.0f;
    #pragma unroll
    for (int r = 0; r < 16; ++r) { v[r] = __expf(v[r] - mx); s += v[r]; }
    #pragma unroll
    for (int off = 32; off > 0; off >>= 1) s += __shfl_xor(s, off, 64);
    if ((t & 63) == 0) red[t >> 6] = s;
    __syncthreads();
    float inv = 1.0f / (red[0] + red[1] + red[2] + red[3]);

    #pragma unroll
    for (int r = 0; r < 16; ++r)
        A[(size_t)n * NN + t + r * 256] = v[r] * inv;
}

// ---------------------------------------------------------------------------
// Kernel 2/3: Yout[b,n,c] = alpha * sum_m A[n,m] * Xin[b,m,c]  (- Xsub[b,n,c])
// Tiled 64x64, 256 threads, 4x4 micro-tile, transposed-A LDS for float4 reads.
// ---------------------------------------------------------------------------
__global__ __launch_bounds__(256) void gemm_ax_kernel(
    const float* __restrict__ A, const float* __restrict__ Xin,
    const float* __restrict__ Xsub, float* __restrict__ Yout, float alpha)
{
    const int n0 = blockIdx.x * 64;
    const int b  = blockIdx.y;
    const int t  = threadIdx.x;
    const int tr = t >> 4;           // 0..15 (output row group)
    const int tc = t & 15;           // 0..15 (output col group)
    const int lr = t >> 4;           // load row-in-chunk
    const int k4 = (t & 15) << 2;    // load col*4

    __shared__ float SAT[64][68];    // SAT[k][r] = A[n0+r][kt+k]
    __shared__ float SX [64][68];    // SX[k][c]  = X[b][kt+k][c]

    float acc[4][4] = {};
    const float* Xb = Xin + (size_t)b * NN * CIN;

    for (int kt = 0; kt < NN; kt += 64) {
        #pragma unroll
        for (int it = 0; it < 4; ++it) {
            int r = lr + it * 16;
            float4 av = *reinterpret_cast<const float4*>(
                A + (size_t)(n0 + r) * NN + kt + k4);
            SAT[k4 + 0][r] = av.x; SAT[k4 + 1][r] = av.y;
            SAT[k4 + 2][r] = av.z; SAT[k4 + 3][r] = av.w;
            float4 xv = *reinterpret_cast<const float4*>(
                Xb + (size_t)(kt + r) * CIN + k4);
            *reinterpret_cast<float4*>(&SX[r][k4]) = xv;
        }
        __syncthreads();
        #pragma unroll 8
        for (int k = 0; k < 64; ++k) {
            float4 a = *reinterpret_cast<const float4*>(&SAT[k][tr << 2]);
            float4 x = *reinterpret_cast<const float4*>(&SX[k][tc << 2]);
            acc[0][0] += a.x * x.x; acc[0][1] += a.x * x.y;
            acc[0][2] += a.x * x.z; acc[0][3] += a.x * x.w;
            acc[1][0] += a.y * x.x; acc[1][1] += a.y * x.y;
            acc[1][2] += a.y * x.z; acc[1][3] += a.y * x.w;
            acc[2][0] += a.z * x.x; acc[2][1] += a.z * x.y;
            acc[2][2] += a.z * x.z; acc[2][3] += a.z * x.w;
            acc[3][0] += a.w * x.x; acc[3][1] += a.w * x.y;
            acc[3][2] += a.w * x.z; acc[3][3] += a.w * x.w;
        }
        __syncthreads();
    }

    #pragma unroll
    for (int i = 0; i < 4; ++i) {
        int n = n0 + (tr << 2) + i;
        #pragma unroll
        for (int j = 0; j < 4; ++j) {
            int c = (tc << 2) + j;
            size_t off = (size_t)b * NN * CIN + (size_t)n * CIN + c;
            float vv = alpha * acc[i][j];
            if (Xsub) vv -= Xsub[off];
            Yout[off] = vv;
        }
    }
}

// ---------------------------------------------------------------------------
// Kernel 4: per-node fused epilogue.
// W_n[k,i,o] = sum_d E[n,d] wp[d,k,i,o]  (built in LDS, 48 KB)
// out[b,n,o] = sum_{k,i} XG[b,n,k,i] * W_n[k,i,o] + sum_d E[n,d] bp[d,o]
// XG: k=0 -> X, k=1 -> Y1, k=2 -> Y2.
// ---------------------------------------------------------------------------
__global__ __launch_bounds__(256) void fused_out_kernel(
    const float* __restrict__ E,  const float* __restrict__ wp,
    const float* __restrict__ bp, const float* __restrict__ X,
    const float* __restrict__ Y1, const float* __restrict__ Y2,
    float* __restrict__ out)
{
    const int n = blockIdx.x;
    const int t = threadIdx.x;
    __shared__ float en[EMB];
    __shared__ float Wn[3 * CIN * COUT];   // 12288 floats = 48 KB
    __shared__ float xgs[BB * 200];        // [16][192] padded to 200

    if (t < EMB) en[t] = E[(size_t)n * EMB + t];
    __syncthreads();

    float enr[EMB];
    #pragma unroll
    for (int d = 0; d < EMB; ++d) enr[d] = en[d];

    // build Wn
    for (int idx = t; idx < 3 * CIN * COUT; idx += 256) {
        float w = 0.0f;
        #pragma unroll
        for (int d = 0; d < EMB; ++d) w += enr[d] * wp[d * 12288 + idx];
        Wn[idx] = w;
    }
    // load XG rows for this node, all batches
    for (int u = t; u < BB * 192; u += 256) {
        int b  = u / 192;
        int ki = u % 192;
        int k  = ki >> 6, i = ki & 63;
        size_t off = (size_t)b * NN * CIN + (size_t)n * CIN + i;
        float val = (k == 0) ? X[off] : (k == 1 ? Y1[off] : Y2[off]);
        xgs[b * 200 + ki] = val;
    }
    __syncthreads();

    const int b  = t >> 4;          // 0..15
    const int oc = (t & 15) << 2;   // 0,4,...,60

    float bias0 = 0, bias1 = 0, bias2 = 0, bias3 = 0;
    #pragma unroll
    for (int d = 0; d < EMB; ++d) {
        const float* bpr = bp + d * COUT + oc;
        bias0 += enr[d] * bpr[0];
        bias1 += enr[d] * bpr[1];
        bias2 += enr[d] * bpr[2];
        bias3 += enr[d] * bpr[3];
    }

    float a0 = bias0, a1 = bias1, a2 = bias2, a3 = bias3;
    #pragma unroll 8
    for (int ki = 0; ki < 192; ++ki) {
        float4 w = *reinterpret_cast<const float4*>(&Wn[ki * 64 + oc]);
        float xv = xgs[b * 200 + ki];
        a0 += xv * w.x; a1 += xv * w.y; a2 += xv * w.z; a3 += xv * w.w;
    }
    float4 r = make_float4(a0, a1, a2, a3);
    *reinterpret_cast<float4*>(&out[((size_t)b * NN + n) * COUT + oc]) = r;
}

// ---------------------------------------------------------------------------
extern "C" void kernel_launch(void* const* d_in, const int* in_sizes, int n_in,
                              void* d_out, int out_size, void* d_ws, size_t ws_size,
                              hipStream_t stream)
{
    const float* X  = (const float*)d_in[0];  // [16,4096,64]
    const float* E  = (const float*)d_in[1];  // [4096,16]
    const float* wp = (const float*)d_in[2];  // [16,3,64,64]
    const float* bp = (const float*)d_in[3];  // [16,64]
    float* out = (float*)d_out;

    char* ws = (char*)d_ws;
    float* A  = (float*)ws;                                              // 64 MB
    float* Y1 = (float*)(ws + (size_t)NN * NN * 4);                      // 16 MB
    float* Y2 = (float*)(ws + (size_t)NN * NN * 4 + (size_t)BB*NN*CIN*4);// 16 MB

    adj_softmax_kernel<<<NN, 256, 0, stream>>>(E, A);
    gemm_ax_kernel<<<dim3(NN / 64, BB), 256, 0, stream>>>(A, X,  nullptr, Y1, 1.0f);
    gemm_ax_kernel<<<dim3(NN / 64, BB), 256, 0, stream>>>(A, Y1, X,       Y2, 2.0f);
    fused_out_kernel<<<NN, 256, 0, stream>>>(E, wp, bp, X, Y1, Y2, out);
}

// Round 2
// 535.153 us; speedup vs baseline: 2.3523x; 2.3523x over previous
//
#include <hip/hip_runtime.h>
#include <cstdint>

#define NN   4096
#define EMB  16
#define CIN  64
#define COUT 64
#define BB   16

typedef __attribute__((ext_vector_type(8))) short short8v;
typedef __attribute__((ext_vector_type(4))) float f32x4;

__device__ inline ushort f2bf(float f) {
    uint32_t u = __builtin_bit_cast(uint32_t, f);
    uint32_t r = (u + 0x7FFFu + ((u >> 16) & 1u)) >> 16;
    return (ushort)r;
}

// ---------------------------------------------------------------------------
// Kernel 1: A = softmax(relu(E @ E^T), axis=1), stored bf16. One block/row.
// ---------------------------------------------------------------------------
__global__ __launch_bounds__(256) void adj_softmax_kernel(
    const float* __restrict__ E, ushort* __restrict__ A)
{
    const int n = blockIdx.x;
    const int t = threadIdx.x;
    __shared__ float en[EMB];
    __shared__ float red[4];

    if (t < EMB) en[t] = E[(size_t)n * EMB + t];
    __syncthreads();

    float v[16];
    float mx = 0.0f;  // relu >= 0
    #pragma unroll
    for (int r = 0; r < 16; ++r) {
        int m = t + r * 256;
        const float4* ep = reinterpret_cast<const float4*>(E + (size_t)m * EMB);
        float4 e0 = ep[0], e1 = ep[1], e2 = ep[2], e3 = ep[3];
        float d = e0.x*en[0] + e0.y*en[1] + e0.z*en[2]  + e0.w*en[3]
                + e1.x*en[4] + e1.y*en[5] + e1.z*en[6]  + e1.w*en[7]
                + e2.x*en[8] + e2.y*en[9] + e2.z*en[10] + e2.w*en[11]
                + e3.x*en[12]+ e3.y*en[13]+ e3.z*en[14] + e3.w*en[15];
        d = fmaxf(d, 0.0f);
        v[r] = d;
        mx = fmaxf(mx, d);
    }
    #pragma unroll
    for (int off = 32; off > 0; off >>= 1) mx = fmaxf(mx, __shfl_xor(mx, off, 64));
    if ((t & 63) == 0) red[t >> 6] = mx;
    __syncthreads();
    mx = fmaxf(fmaxf(red[0], red[1]), fmaxf(red[2], red[3]));
    __syncthreads();

    float s = 0.0f;
    #pragma unroll
    for (int r = 0; r < 16; ++r) { v[r] = __expf(v[r] - mx); s += v[r]; }
    #pragma unroll
    for (int off = 32; off > 0; off >>= 1) s += __shfl_xor(s, off, 64);
    if ((t & 63) == 0) red[t >> 6] = s;
    __syncthreads();
    float inv = 1.0f / (red[0] + red[1] + red[2] + red[3]);

    #pragma unroll
    for (int r = 0; r < 16; ++r)
        A[(size_t)n * NN + t + r * 256] = f2bf(v[r] * inv);
}

// ---------------------------------------------------------------------------
// Kernel 2: XT[b][c][m] (bf16) = X[b][m][c] (f32) — transpose + convert.
// ---------------------------------------------------------------------------
__global__ __launch_bounds__(256) void transpose_conv_kernel(
    const float* __restrict__ X, ushort* __restrict__ XT)
{
    const int m0 = blockIdx.x * 64;
    const int b  = blockIdx.y;
    const int t  = threadIdx.x;
    __shared__ float tile[64][68];
    const float* Xb = X + (size_t)b * NN * CIN;

    #pragma unroll
    for (int it = 0; it < 4; ++it) {
        int r  = (t >> 4) + it * 16;
        int c4 = (t & 15) * 4;
        float4 v = *reinterpret_cast<const float4*>(Xb + (size_t)(m0 + r) * CIN + c4);
        *reinterpret_cast<float4*>(&tile[r][c4]) = v;
    }
    __syncthreads();
    #pragma unroll
    for (int it = 0; it < 2; ++it) {
        int c  = (t >> 3) + it * 32;
        int k8 = (t & 7) * 8;
        ushort4 p0, p1;
        p0.x = f2bf(tile[k8+0][c]); p0.y = f2bf(tile[k8+1][c]);
        p0.z = f2bf(tile[k8+2][c]); p0.w = f2bf(tile[k8+3][c]);
        p1.x = f2bf(tile[k8+4][c]); p1.y = f2bf(tile[k8+5][c]);
        p1.z = f2bf(tile[k8+6][c]); p1.w = f2bf(tile[k8+7][c]);
        ushort* dst = XT + ((size_t)b * CIN + c) * NN + m0 + k8;
        *reinterpret_cast<ushort4*>(dst)     = p0;
        *reinterpret_cast<ushort4*>(dst + 4) = p1;
    }
}

// ---------------------------------------------------------------------------
// Kernel 3/4: MFMA GEMM.  Yn[b,m,c] = alpha*sum_k A[m,k]*BT[b,c,k] (- Xsub)
// BM=128, BN=64(one batch), BK=64, 256 thr (4 waves), wave = 32x64 (2x4 frags
// of 16x16x32).  Padded LDS rows (+8 bf16) => 2-way (free) bank aliasing.
// XCD-aware block swizzle: all 16 batches of one m-tile share an XCD so the
// 4 MB A-slice stays L2-resident.
// Optionally writes Yt[b][c][m] bf16 (transposed) for the next GEMM.
// ---------------------------------------------------------------------------
__global__ __launch_bounds__(256) void gemm_mfma_kernel(
    const ushort* __restrict__ A, const ushort* __restrict__ BT,
    const float* __restrict__ Xsub, float* __restrict__ Yn,
    ushort* __restrict__ Yt, float alpha)
{
    __shared__ ushort Alds[128][72];
    __shared__ ushort Blds[64][72];

    const int i = blockIdx.x;                       // 0..511
    const int m_tile = (i & 7) * 4 + ((i >> 3) & 3);// same m_tile -> same XCD
    const int b = i >> 5;
    const int n0 = m_tile * 128;
    const int t = threadIdx.x;
    const int w = t >> 6;
    const int l = t & 63;

    const ushort* Ab = A  + (size_t)n0 * NN;
    const ushort* Bb = BT + (size_t)b * CIN * NN;

    f32x4 acc[2][4];
    #pragma unroll
    for (int mi = 0; mi < 2; ++mi)
        #pragma unroll
        for (int ni = 0; ni < 4; ++ni)
            acc[mi][ni] = (f32x4){0.f, 0.f, 0.f, 0.f};

    const int arow = t >> 3;         // 0..31
    const int acol = (t & 7) * 8;    // element offset in k
    const int xc   = t >> 2;         // 0..63
    const int xk   = (t & 3) * 16;   // element offset in k

    for (int kt = 0; kt < NN; kt += 64) {
        #pragma unroll
        for (int it = 0; it < 4; ++it) {
            int r = arow + it * 32;
            uint4 v = *reinterpret_cast<const uint4*>(Ab + (size_t)r * NN + kt + acol);
            *reinterpret_cast<uint4*>(&Alds[r][acol]) = v;
        }
        {
            const ushort* src = Bb + (size_t)xc * NN + kt + xk;
            uint4 v0 = *reinterpret_cast<const uint4*>(src);
            uint4 v1 = *reinterpret_cast<const uint4*>(src + 8);
            *reinterpret_cast<uint4*>(&Blds[xc][xk])     = v0;
            *reinterpret_cast<uint4*>(&Blds[xc][xk + 8]) = v1;
        }
        __syncthreads();

        const int rl = l & 15;
        #pragma unroll
        for (int ks = 0; ks < 64; ks += 32) {
            const int koff = ks + (l >> 4) * 8;
            short8v af[2], bfr[4];
            #pragma unroll
            for (int mi = 0; mi < 2; ++mi)
                af[mi] = *reinterpret_cast<const short8v*>(&Alds[w * 32 + mi * 16 + rl][koff]);
            #pragma unroll
            for (int ni = 0; ni < 4; ++ni)
                bfr[ni] = *reinterpret_cast<const short8v*>(&Blds[ni * 16 + rl][koff]);
            #pragma unroll
            for (int mi = 0; mi < 2; ++mi)
                #pragma unroll
                for (int ni = 0; ni < 4; ++ni)
                    acc[mi][ni] = __builtin_amdgcn_mfma_f32_16x16x32_bf16(
                        af[mi], bfr[ni], acc[mi][ni], 0, 0, 0);
        }
        __syncthreads();
    }

    // Epilogue: C/D layout col=lane&15, row=(lane>>4)*4+reg [m89-verified]
    const int rl = l & 15;
    const int rquad = (l >> 4) * 4;
    #pragma unroll
    for (int mi = 0; mi < 2; ++mi) {
        int row0 = w * 32 + mi * 16 + rquad;
        #pragma unroll
        for (int ni = 0; ni < 4; ++ni) {
            int c = ni * 16 + rl;
            float vals[4];
            #pragma unroll
            for (int j = 0; j < 4; ++j) {
                int row = n0 + row0 + j;
                size_t off = ((size_t)b * NN + row) * CIN + c;
                float vv = alpha * acc[mi][ni][j];
                if (Xsub) vv -= Xsub[off];
                Yn[off] = vv;
                vals[j] = vv;
            }
            if (Yt) {
                ushort4 pk;
                pk.x = f2bf(vals[0]); pk.y = f2bf(vals[1]);
                pk.z = f2bf(vals[2]); pk.w = f2bf(vals[3]);
                *reinterpret_cast<ushort4*>(
                    Yt + ((size_t)b * CIN + c) * NN + n0 + row0) = pk;
            }
        }
    }
}

// ---------------------------------------------------------------------------
// Kernel 5: per-node fused epilogue (unchanged from passing round-1 version).
// ---------------------------------------------------------------------------
__global__ __launch_bounds__(256) void fused_out_kernel(
    const float* __restrict__ E,  const float* __restrict__ wp,
    const float* __restrict__ bp, const float* __restrict__ X,
    const float* __restrict__ Y1, const float* __restrict__ Y2,
    float* __restrict__ out)
{
    const int n = blockIdx.x;
    const int t = threadIdx.x;
    __shared__ float en[EMB];
    __shared__ float Wn[3 * CIN * COUT];   // 48 KB
    __shared__ float xgs[BB * 200];

    if (t < EMB) en[t] = E[(size_t)n * EMB + t];
    __syncthreads();

    float enr[EMB];
    #pragma unroll
    for (int d = 0; d < EMB; ++d) enr[d] = en[d];

    for (int idx = t; idx < 3 * CIN * COUT; idx += 256) {
        float w = 0.0f;
        #pragma unroll
        for (int d = 0; d < EMB; ++d) w += enr[d] * wp[d * 12288 + idx];
        Wn[idx] = w;
    }
    for (int u = t; u < BB * 192; u += 256) {
        int b  = u / 192;
        int ki = u % 192;
        int k  = ki >> 6, i = ki & 63;
        size_t off = (size_t)b * NN * CIN + (size_t)n * CIN + i;
        float val = (k == 0) ? X[off] : (k == 1 ? Y1[off] : Y2[off]);
        xgs[b * 200 + ki] = val;
    }
    __syncthreads();

    const int b  = t >> 4;
    const int oc = (t & 15) << 2;

    float bias0 = 0, bias1 = 0, bias2 = 0, bias3 = 0;
    #pragma unroll
    for (int d = 0; d < EMB; ++d) {
        const float* bpr = bp + d * COUT + oc;
        bias0 += enr[d] * bpr[0];
        bias1 += enr[d] * bpr[1];
        bias2 += enr[d] * bpr[2];
        bias3 += enr[d] * bpr[3];
    }

    float a0 = bias0, a1 = bias1, a2 = bias2, a3 = bias3;
    #pragma unroll 8
    for (int ki = 0; ki < 192; ++ki) {
        float4 w = *reinterpret_cast<const float4*>(&Wn[ki * 64 + oc]);
        float xv = xgs[b * 200 + ki];
        a0 += xv * w.x; a1 += xv * w.y; a2 += xv * w.z; a3 += xv * w.w;
    }
    float4 r = make_float4(a0, a1, a2, a3);
    *reinterpret_cast<float4*>(&out[((size_t)b * NN + n) * COUT + oc]) = r;
}

// ---------------------------------------------------------------------------
extern "C" void kernel_launch(void* const* d_in, const int* in_sizes, int n_in,
                              void* d_out, int out_size, void* d_ws, size_t ws_size,
                              hipStream_t stream)
{
    const float* X  = (const float*)d_in[0];  // [16,4096,64]
    const float* E  = (const float*)d_in[1];  // [4096,16]
    const float* wp = (const float*)d_in[2];  // [16,3,64,64]
    const float* bp = (const float*)d_in[3];  // [16,64]
    float* out = (float*)d_out;

    char* ws = (char*)d_ws;
    size_t off = 0;
    ushort* Abf = (ushort*)(ws + off); off += (size_t)NN * NN * 2;         // 32 MB
    ushort* XT  = (ushort*)(ws + off); off += (size_t)BB * CIN * NN * 2;   //  8 MB
    ushort* Y1T = (ushort*)(ws + off); off += (size_t)BB * CIN * NN * 2;   //  8 MB
    float*  Y1  = (float*) (ws + off); off += (size_t)BB * NN * CIN * 4;   // 16 MB
    float*  Y2  = (float*) (ws + off);                                     // 16 MB

    adj_softmax_kernel  <<<NN, 256, 0, stream>>>(E, Abf);
    transpose_conv_kernel<<<dim3(NN / 64, BB), 256, 0, stream>>>(X, XT);
    gemm_mfma_kernel    <<<512, 256, 0, stream>>>(Abf, XT,  nullptr, Y1, Y1T, 1.0f);
    gemm_mfma_kernel    <<<512, 256, 0, stream>>>(Abf, Y1T, X,       Y2, nullptr, 2.0f);
    fused_out_kernel    <<<NN, 256, 0, stream>>>(E, wp, bp, X, Y1, Y2, out);
}

// Round 3
// 395.316 us; speedup vs baseline: 3.1844x; 1.3537x over previous
//
#include <hip/hip_runtime.h>
#include <cstdint>

#define NN   4096
#define EMB  16
#define CIN  64
#define COUT 64
#define BB   16

typedef __attribute__((ext_vector_type(8))) short short8v;
typedef __attribute__((ext_vector_type(4))) float f32x4;

__device__ inline ushort f2bf(float f) {
    uint32_t u = __builtin_bit_cast(uint32_t, f);
    uint32_t r = (u + 0x7FFFu + ((u >> 16) & 1u)) >> 16;
    return (ushort)r;
}

// ---------------------------------------------------------------------------
// Kernel 1: A = softmax(relu(E @ E^T), axis=1), stored bf16. One block/row.
// ---------------------------------------------------------------------------
__global__ __launch_bounds__(256) void adj_softmax_kernel(
    const float* __restrict__ E, ushort* __restrict__ A)
{
    const int n = blockIdx.x;
    const int t = threadIdx.x;
    __shared__ float en[EMB];
    __shared__ float red[4];

    if (t < EMB) en[t] = E[(size_t)n * EMB + t];
    __syncthreads();

    float v[16];
    float mx = 0.0f;  // relu >= 0
    #pragma unroll
    for (int r = 0; r < 16; ++r) {
        int m = t + r * 256;
        const float4* ep = reinterpret_cast<const float4*>(E + (size_t)m * EMB);
        float4 e0 = ep[0], e1 = ep[1], e2 = ep[2], e3 = ep[3];
        float d = e0.x*en[0] + e0.y*en[1] + e0.z*en[2]  + e0.w*en[3]
                + e1.x*en[4] + e1.y*en[5] + e1.z*en[6]  + e1.w*en[7]
                + e2.x*en[8] + e2.y*en[9] + e2.z*en[10] + e2.w*en[11]
                + e3.x*en[12]+ e3.y*en[13]+ e3.z*en[14] + e3.w*en[15];
        d = fmaxf(d, 0.0f);
        v[r] = d;
        mx = fmaxf(mx, d);
    }
    #pragma unroll
    for (int off = 32; off > 0; off >>= 1) mx = fmaxf(mx, __shfl_xor(mx, off, 64));
    if ((t & 63) == 0) red[t >> 6] = mx;
    __syncthreads();
    mx = fmaxf(fmaxf(red[0], red[1]), fmaxf(red[2], red[3]));
    __syncthreads();

    float s = 0.0f;
    #pragma unroll
    for (int r = 0; r < 16; ++r) { v[r] = __expf(v[r] - mx); s += v[r]; }
    #pragma unroll
    for (int off = 32; off > 0; off >>= 1) s += __shfl_xor(s, off, 64);
    if ((t & 63) == 0) red[t >> 6] = s;
    __syncthreads();
    float inv = 1.0f / (red[0] + red[1] + red[2] + red[3]);

    #pragma unroll
    for (int r = 0; r < 16; ++r)
        A[(size_t)n * NN + t + r * 256] = f2bf(v[r] * inv);
}

// ---------------------------------------------------------------------------
// Kernel 2: XT[b][c][m] (bf16) = X[b][m][c] (f32) — transpose + convert.
// ---------------------------------------------------------------------------
__global__ __launch_bounds__(256) void transpose_conv_kernel(
    const float* __restrict__ X, ushort* __restrict__ XT)
{
    const int m0 = blockIdx.x * 64;
    const int b  = blockIdx.y;
    const int t  = threadIdx.x;
    __shared__ float tile[64][68];
    const float* Xb = X + (size_t)b * NN * CIN;

    #pragma unroll
    for (int it = 0; it < 4; ++it) {
        int r  = (t >> 4) + it * 16;
        int c4 = (t & 15) * 4;
        float4 v = *reinterpret_cast<const float4*>(Xb + (size_t)(m0 + r) * CIN + c4);
        *reinterpret_cast<float4*>(&tile[r][c4]) = v;
    }
    __syncthreads();
    #pragma unroll
    for (int it = 0; it < 2; ++it) {
        int c  = (t >> 3) + it * 32;
        int k8 = (t & 7) * 8;
        ushort4 p0, p1;
        p0.x = f2bf(tile[k8+0][c]); p0.y = f2bf(tile[k8+1][c]);
        p0.z = f2bf(tile[k8+2][c]); p0.w = f2bf(tile[k8+3][c]);
        p1.x = f2bf(tile[k8+4][c]); p1.y = f2bf(tile[k8+5][c]);
        p1.z = f2bf(tile[k8+6][c]); p1.w = f2bf(tile[k8+7][c]);
        ushort* dst = XT + ((size_t)b * CIN + c) * NN + m0 + k8;
        *reinterpret_cast<ushort4*>(dst)     = p0;
        *reinterpret_cast<ushort4*>(dst + 4) = p1;
    }
}

// ---------------------------------------------------------------------------
// Kernel 3: wpT[d][o][ki] (bf16) = wp[d][ki][o] (f32).  grid 64 x 256.
// ---------------------------------------------------------------------------
__global__ __launch_bounds__(256) void wp_pack_kernel(
    const float* __restrict__ wp, ushort* __restrict__ wpT)
{
    const int d  = blockIdx.x >> 2;
    const int q  = blockIdx.x & 3;
    const int o  = q * 16 + (threadIdx.x >> 4);
    const int k0 = (threadIdx.x & 15) * 12;
    const float* src = wp + (size_t)d * 12288 + o;
    ushort* dst = wpT + ((size_t)d * 64 + o) * 192 + k0;
    #pragma unroll
    for (int j = 0; j < 12; ++j) dst[j] = f2bf(src[(size_t)(k0 + j) * 64]);
}

// ---------------------------------------------------------------------------
// Kernel 4/5: MFMA GEMM.  acc = sum_k A[m,k]*BT[b,c,k]; writes ONLY the
// bf16 transposed result Yt[b][c][m] = alpha*acc (- Xsub[b,m,c]).
// ---------------------------------------------------------------------------
__global__ __launch_bounds__(256) void gemm_mfma_kernel(
    const ushort* __restrict__ A, const ushort* __restrict__ BT,
    const float* __restrict__ Xsub, ushort* __restrict__ Yt, float alpha)
{
    __shared__ ushort Alds[128][72];
    __shared__ ushort Blds[64][72];

    const int i = blockIdx.x;                       // 0..511
    const int m_tile = (i & 7) * 4 + ((i >> 3) & 3);// same m_tile -> same XCD
    const int b = i >> 5;
    const int n0 = m_tile * 128;
    const int t = threadIdx.x;
    const int w = t >> 6;
    const int l = t & 63;

    const ushort* Ab = A  + (size_t)n0 * NN;
    const ushort* Bb = BT + (size_t)b * CIN * NN;

    f32x4 acc[2][4];
    #pragma unroll
    for (int mi = 0; mi < 2; ++mi)
        #pragma unroll
        for (int ni = 0; ni < 4; ++ni)
            acc[mi][ni] = (f32x4){0.f, 0.f, 0.f, 0.f};

    const int arow = t >> 3;         // 0..31
    const int acol = (t & 7) * 8;
    const int xc   = t >> 2;         // 0..63
    const int xk   = (t & 3) * 16;

    for (int kt = 0; kt < NN; kt += 64) {
        #pragma unroll
        for (int it = 0; it < 4; ++it) {
            int r = arow + it * 32;
            uint4 v = *reinterpret_cast<const uint4*>(Ab + (size_t)r * NN + kt + acol);
            *reinterpret_cast<uint4*>(&Alds[r][acol]) = v;
        }
        {
            const ushort* src = Bb + (size_t)xc * NN + kt + xk;
            uint4 v0 = *reinterpret_cast<const uint4*>(src);
            uint4 v1 = *reinterpret_cast<const uint4*>(src + 8);
            *reinterpret_cast<uint4*>(&Blds[xc][xk])     = v0;
            *reinterpret_cast<uint4*>(&Blds[xc][xk + 8]) = v1;
        }
        __syncthreads();

        const int rl = l & 15;
        #pragma unroll
        for (int ks = 0; ks < 64; ks += 32) {
            const int koff = ks + (l >> 4) * 8;
            short8v af[2], bfr[4];
            #pragma unroll
            for (int mi = 0; mi < 2; ++mi)
                af[mi] = *reinterpret_cast<const short8v*>(&Alds[w * 32 + mi * 16 + rl][koff]);
            #pragma unroll
            for (int ni = 0; ni < 4; ++ni)
                bfr[ni] = *reinterpret_cast<const short8v*>(&Blds[ni * 16 + rl][koff]);
            #pragma unroll
            for (int mi = 0; mi < 2; ++mi)
                #pragma unroll
                for (int ni = 0; ni < 4; ++ni)
                    acc[mi][ni] = __builtin_amdgcn_mfma_f32_16x16x32_bf16(
                        af[mi], bfr[ni], acc[mi][ni], 0, 0, 0);
        }
        __syncthreads();
    }

    // Epilogue: C/D layout col=lane&15, row=(lane>>4)*4+reg
    const int rl = l & 15;
    const int rquad = (l >> 4) * 4;
    #pragma unroll
    for (int mi = 0; mi < 2; ++mi) {
        int row0 = w * 32 + mi * 16 + rquad;
        #pragma unroll
        for (int ni = 0; ni < 4; ++ni) {
            int c = ni * 16 + rl;
            ushort4 pk;
            #pragma unroll
            for (int j = 0; j < 4; ++j) {
                int row = n0 + row0 + j;
                float vv = alpha * acc[mi][ni][j];
                if (Xsub) vv -= Xsub[((size_t)b * NN + row) * CIN + c];
                ((ushort*)&pk)[j] = f2bf(vv);
            }
            *reinterpret_cast<ushort4*>(
                Yt + ((size_t)b * CIN + c) * NN + n0 + row0) = pk;
        }
    }
}

// ---------------------------------------------------------------------------
// Kernel 6: apply.  out[b,n,o] = sum_d E[n,d]*( XG[b,n,:]@wpT[d] + bp[d,o] )
// Block: 64 flat rows (one b), 4 waves; wave w owns rows w*16..w*16+16, all
// 64 cols.  A-frags (rows x 192k) hoisted to regs, reused over the 16-d loop.
// wpT d-slice (24 KB) staged to LDS per d.
// ---------------------------------------------------------------------------
__global__ __launch_bounds__(256) void apply_kernel(
    const ushort* __restrict__ XT, const ushort* __restrict__ Y1T,
    const ushort* __restrict__ Y2T, const ushort* __restrict__ wpT,
    const float* __restrict__ E, const float* __restrict__ bp,
    float* __restrict__ out)
{
    __shared__ ushort Alds[64][200];
    __shared__ ushort Wlds[64][200];
    __shared__ float  Elds[64][17];
    __shared__ float  bplds[16 * 64];

    const int r0 = blockIdx.x * 64;
    const int b  = r0 >> 12;
    const int n0 = r0 & (NN - 1);
    const int t  = threadIdx.x;
    const int w  = t >> 6;
    const int l  = t & 63;

    // stage E tile (64 x 16 f32) and bp (16 x 64 f32)
    {
        float4 ev = *reinterpret_cast<const float4*>(E + (size_t)n0 * EMB + t * 4);
        int rr = t >> 2, dd = (t & 3) * 4;
        Elds[rr][dd + 0] = ev.x; Elds[rr][dd + 1] = ev.y;
        Elds[rr][dd + 2] = ev.z; Elds[rr][dd + 3] = ev.w;
        float4 bv = *reinterpret_cast<const float4*>(bp + t * 4);
        *reinterpret_cast<float4*>(&bplds[t * 4]) = bv;
    }
    // stage A tile: rows n0..n0+63, k = kslot*64 + c, from [b][c][m] layouts
    {
        const int c  = t >> 2;
        const int mg = (t & 3) * 16;
        const size_t base = ((size_t)b * CIN + c) * NN + n0 + mg;
        const ushort* __restrict__ srcs[3] = {XT, Y1T, Y2T};
        #pragma unroll
        for (int ks = 0; ks < 3; ++ks) {
            short8v v0 = *reinterpret_cast<const short8v*>(srcs[ks] + base);
            short8v v1 = *reinterpret_cast<const short8v*>(srcs[ks] + base + 8);
            #pragma unroll
            for (int j = 0; j < 8; ++j) Alds[mg + j][ks * 64 + c] = (ushort)v0[j];
            #pragma unroll
            for (int j = 0; j < 8; ++j) Alds[mg + 8 + j][ks * 64 + c] = (ushort)v1[j];
        }
    }
    __syncthreads();

    const int rl = l & 15;
    const int kq = (l >> 4) * 8;

    // hoist A-frags: 6 k-steps of 32
    short8v af[6];
    #pragma unroll
    for (int ks = 0; ks < 6; ++ks)
        af[ks] = *reinterpret_cast<const short8v*>(&Alds[w * 16 + rl][ks * 32 + kq]);

    f32x4 mainacc[4];
    #pragma unroll
    for (int ni = 0; ni < 4; ++ni) mainacc[ni] = (f32x4){0.f, 0.f, 0.f, 0.f};

    const int wo = t >> 2;           // 0..63 (o for staging)
    const int wk = (t & 3) * 48;     // ki chunk for staging

    for (int d = 0; d < EMB; ++d) {
        __syncthreads();   // previous-iteration Wlds reads complete
        {
            const ushort* src = wpT + ((size_t)(d * 64 + wo)) * 192 + wk;
            #pragma unroll
            for (int j = 0; j < 6; ++j) {
                short8v v = *reinterpret_cast<const short8v*>(src + j * 8);
                *reinterpret_cast<short8v*>(&Wlds[wo][wk + j * 8]) = v;
            }
        }
        __syncthreads();

        f32x4 tmp[4];
        #pragma unroll
        for (int ni = 0; ni < 4; ++ni) tmp[ni] = (f32x4){0.f, 0.f, 0.f, 0.f};
        #pragma unroll
        for (int ks = 0; ks < 6; ++ks) {
            #pragma unroll
            for (int ni = 0; ni < 4; ++ni) {
                short8v bfr = *reinterpret_cast<const short8v*>(
                    &Wlds[ni * 16 + rl][ks * 32 + kq]);
                tmp[ni] = __builtin_amdgcn_mfma_f32_16x16x32_bf16(
                    af[ks], bfr, tmp[ni], 0, 0, 0);
            }
        }
        float e[4];
        #pragma unroll
        for (int j = 0; j < 4; ++j) e[j] = Elds[w * 16 + (l >> 4) * 4 + j][d];
        #pragma unroll
        for (int ni = 0; ni < 4; ++ni)
            #pragma unroll
            for (int j = 0; j < 4; ++j)
                mainacc[ni][j] += e[j] * tmp[ni][j];
    }

    // bias + store
    const int lr4 = (l >> 4) * 4;
    #pragma unroll
    for (int ni = 0; ni < 4; ++ni) {
        int col = ni * 16 + rl;
        #pragma unroll
        for (int j = 0; j < 4; ++j) {
            int locrow = w * 16 + lr4 + j;
            float bias = 0.0f;
            #pragma unroll
            for (int d = 0; d < EMB; ++d)
                bias += Elds[locrow][d] * bplds[d * 64 + col];
            out[((size_t)b * NN + n0 + locrow) * COUT + col] = mainacc[ni][j] + bias;
        }
    }
}

// ---------------------------------------------------------------------------
extern "C" void kernel_launch(void* const* d_in, const int* in_sizes, int n_in,
                              void* d_out, int out_size, void* d_ws, size_t ws_size,
                              hipStream_t stream)
{
    const float* X  = (const float*)d_in[0];  // [16,4096,64]
    const float* E  = (const float*)d_in[1];  // [4096,16]
    const float* wp = (const float*)d_in[2];  // [16,3,64,64]
    const float* bp = (const float*)d_in[3];  // [16,64]
    float* out = (float*)d_out;

    char* ws = (char*)d_ws;
    size_t off = 0;
    ushort* Abf = (ushort*)(ws + off); off += (size_t)NN * NN * 2;        // 32 MB
    ushort* XT  = (ushort*)(ws + off); off += (size_t)BB * CIN * NN * 2;  //  8 MB
    ushort* Y1T = (ushort*)(ws + off); off += (size_t)BB * CIN * NN * 2;  //  8 MB
    ushort* Y2T = (ushort*)(ws + off); off += (size_t)BB * CIN * NN * 2;  //  8 MB
    ushort* wpT = (ushort*)(ws + off);                                    // 384 KB

    adj_softmax_kernel   <<<NN, 256, 0, stream>>>(E, Abf);
    transpose_conv_kernel<<<dim3(NN / 64, BB), 256, 0, stream>>>(X, XT);
    wp_pack_kernel       <<<64, 256, 0, stream>>>(wp, wpT);
    gemm_mfma_kernel     <<<512, 256, 0, stream>>>(Abf, XT,  nullptr, Y1T, 1.0f);
    gemm_mfma_kernel     <<<512, 256, 0, stream>>>(Abf, Y1T, X,       Y2T, 2.0f);
    apply_kernel         <<<1024, 256, 0, stream>>>(XT, Y1T, Y2T, wpT, E, bp, out);
}